// Round 11
// baseline (475.714 us; speedup 1.0000x reference)
//
#include <hip/hip_runtime.h>

typedef unsigned short u16;
typedef unsigned int u32;
typedef float f32x4 __attribute__((ext_vector_type(4)));
typedef __bf16 bf16x8 __attribute__((ext_vector_type(8)));

#define DEV static __device__ __forceinline__

DEV u16 f2bf(float f) {
  u32 u = __builtin_bit_cast(u32, f);
  u += 0x7fffu + ((u >> 16) & 1u);
  return (u16)(u >> 16);
}

DEV float bf2f(u16 v) {
  u32 u = ((u32)v) << 16;
  return __builtin_bit_cast(float, u);
}

DEV void gload_lds16(const void* g, void* l) {
  __builtin_amdgcn_global_load_lds(
      (const __attribute__((address_space(1))) u32*)g,
      (__attribute__((address_space(3))) u32*)l, 16, 0, 0);
}

// ---------------- convert kernels ----------------

__global__ __launch_bounds__(256) void cvt_bf16(const float* __restrict__ in,
                                                u16* __restrict__ out, int n4) {
  int i = blockIdx.x * 256 + threadIdx.x;
  const int stride = gridDim.x * 256;
  for (; i < n4; i += stride) {
    const float4 v = ((const float4*)in)[i];
    ushort4 o;
    o.x = f2bf(v.x); o.y = f2bf(v.y); o.z = f2bf(v.z); o.w = f2bf(v.w);
    ((ushort4*)out)[i] = o;
  }
}

// in [K,N] fp32 -> out [N,K] bf16 (transposed)
__global__ __launch_bounds__(256) void cvtT_bf16(const float* __restrict__ in,
                                                 u16* __restrict__ out, int K, int N) {
  int i = blockIdx.x * 256 + threadIdx.x;
  if (i >= N * K) return;
  int n = i / K, k = i - n * K;
  out[i] = f2bf(in[(long)k * N + n]);
}

// biasM[h][p] = bias_table[rel_idx[p]*12 + h], p < 2401
__global__ __launch_bounds__(256) void bias_pre(const float* __restrict__ bias_table,
                                                const int* __restrict__ rel_idx,
                                                float* __restrict__ biasM) {
  int i = blockIdx.x * 256 + threadIdx.x;
  if (i >= 12 * 2401) return;
  int h = i / 2401, p = i - h * 2401;
  biasM[i] = bias_table[rel_idx[p] * 12 + h];
}

// ---------------- 256x256 deep-pipelined GEMM (round-6 best: 207-210 us) ---
// LDS layout (per 32KB buffer): A = 128 lines x 128B (2 m-rows/line), B @+16384.
// Swizzle: (row, 16B-blk b) -> line = row>>1, slot = (row&1)*4+b, slot ^= line&7.
// Conflict-free (measured 0). Depth-3 staging, vmcnt(4) at bottom so tiles
// kt+1,kt+2 are published entering iter kt+1 -> next tile's fragments
// prefetched in-register DURING iter kt (ping-pong X/Y).
template <bool OUT_BF16>
__global__ __launch_bounds__(512, 2) void gemm256(
    const u16* __restrict__ A, const u16* __restrict__ BT,
    void* __restrict__ C, const float* __restrict__ bias,
    int M, int N, int K, int nbn) {
  __shared__ alignas(16) char lds[131072];
  const int t = threadIdx.x;
  const int w = t >> 6, l = t & 63, lr = l & 15, lhi = l >> 4;
  const int wr = w >> 2, wc = w & 3;

  // bijective XCD-chunked swizzle
  const int nwg = gridDim.x;
  const int q = nwg >> 3, r = nwg & 7;
  const int xcd = blockIdx.x & 7, lid = blockIdx.x >> 3;
  const int swz = (xcd < r ? xcd * (q + 1) : r * (q + 1) + (xcd - r) * q) + lid;
  const int bm = swz / nbn, bn = swz % nbn;

  const int T = K >> 5;  // K-tiles of 32 (K=768 -> 24, even)
  const long Kb = (long)K * 2;

  // staging source (inverse swizzle; global_load_lds dest is linear)
  const int unswz = (l & 7) ^ (l >> 3);
  const int arow = 2 * (l >> 3) + (unswz >> 2);
  const int acolb = (unswz & 3) << 4;
  const char* gA0 = (const char*)A + (long)(bm * 256 + w * 32 + arow) * Kb + acolb;
  const char* gA1 = gA0 + 16 * Kb;
  const char* gB0 = (const char*)BT + (long)(bn * 256 + w * 32 + arow) * Kb + acolb;
  const char* gB1 = gB0 + 16 * Kb;
  const int ldA0 = w * 2048, ldA1 = w * 2048 + 1024;
  const int ldB0 = 16384 + w * 2048, ldB1 = 16384 + w * 2048 + 1024;

#define STAGE(tt)                               \
  {                                             \
    const int bb = ((tt) & 3) * 32768;          \
    const long ko = (long)(tt) * 64;            \
    gload_lds16(gA0 + ko, lds + bb + ldA0);     \
    gload_lds16(gA1 + ko, lds + bb + ldA1);     \
    gload_lds16(gB0 + ko, lds + bb + ldB0);     \
    gload_lds16(gB1 + ko, lds + bb + ldB1);     \
  }
#define BAR                                  \
  asm volatile("" ::: "memory");             \
  __builtin_amdgcn_s_barrier();              \
  asm volatile("" ::: "memory")

  // frag read offsets (swizzled)
  const int rblk = ((((lr & 1) << 2) | lhi) ^ (lr >> 1));
  const int aoff0 = (wr * 64 + (lr >> 1)) * 128 + rblk * 16;          // + mt*1024
  const int boff0 = 16384 + (wc * 32 + (lr >> 1)) * 128 + rblk * 16;  // + nt*1024

  f32x4 acc[8][4];
#pragma unroll
  for (int m = 0; m < 8; ++m)
#pragma unroll
    for (int n = 0; n < 4; ++n) acc[m][n] = (f32x4){0.f, 0.f, 0.f, 0.f};
  bf16x8 afrX[4], bfrX[4], afrY[4], bfrY[4];

#define CLUSTER1(S)                                                        \
  __builtin_amdgcn_s_setprio(1);                                           \
  _Pragma("unroll") for (int m = 0; m < 4; ++m)                            \
      _Pragma("unroll") for (int n = 0; n < 4; ++n)                        \
          acc[m][n] = __builtin_amdgcn_mfma_f32_16x16x32_bf16(             \
              afr##S[m], bfr##S[n], acc[m][n], 0, 0, 0);                   \
  __builtin_amdgcn_s_setprio(0)
#define CLUSTER2(S)                                                        \
  __builtin_amdgcn_s_setprio(1);                                           \
  _Pragma("unroll") for (int m = 0; m < 4; ++m)                            \
      _Pragma("unroll") for (int n = 0; n < 4; ++n)                        \
          acc[m + 4][n] = __builtin_amdgcn_mfma_f32_16x16x32_bf16(         \
              afr2[m], bfr##S[n], acc[m + 4][n], 0, 0, 0);                 \
  __builtin_amdgcn_s_setprio(0)

#define BODY(kt, S, R)                                                     \
  {                                                                        \
    if ((kt) + 3 < T) STAGE((kt) + 3);                                     \
    const int bbc = ((kt) & 3) * 32768;                                    \
    const int nx = ((kt) + 1 < T) ? (kt) + 1 : (kt);                       \
    const int bbn = (nx & 3) * 32768;                                      \
    bf16x8 afr2[4];                                                        \
    _Pragma("unroll") for (int m = 0; m < 4; ++m)                          \
        afr2[m] = *(const bf16x8*)(lds + bbc + aoff0 + (m + 4) * 1024);    \
    CLUSTER1(S);                                                           \
    _Pragma("unroll") for (int n = 0; n < 4; ++n)                          \
        bfr##R[n] = *(const bf16x8*)(lds + bbn + boff0 + n * 1024);        \
    CLUSTER2(S);                                                           \
    _Pragma("unroll") for (int m = 0; m < 4; ++m)                          \
        afr##R[m] = *(const bf16x8*)(lds + bbn + aoff0 + m * 1024);        \
    if ((kt) + 3 < T) {                                                    \
      asm volatile("s_waitcnt vmcnt(4)" ::: "memory");                     \
    } else {                                                               \
      asm volatile("s_waitcnt vmcnt(0)" ::: "memory");                     \
    }                                                                      \
    BAR;                                                                   \
  }

  STAGE(0); STAGE(1); STAGE(2);
  asm volatile("s_waitcnt vmcnt(4)" ::: "memory");
  BAR;
#pragma unroll
  for (int n = 0; n < 4; ++n) bfrX[n] = *(const bf16x8*)(lds + boff0 + n * 1024);
#pragma unroll
  for (int m = 0; m < 4; ++m) afrX[m] = *(const bf16x8*)(lds + aoff0 + m * 1024);

  for (int i = 0; i < T / 2; ++i) {
    BODY(2 * i, X, Y);
    BODY(2 * i + 1, Y, X);
  }
#undef STAGE
#undef BAR
#undef CLUSTER1
#undef CLUSTER2
#undef BODY

  const int row0 = bm * 256 + wr * 128 + 4 * lhi;
  const int col0 = bn * 256 + wc * 64 + lr;
  if (OUT_BF16) {
    u16* Cc = (u16*)C;
#pragma unroll
    for (int m = 0; m < 8; ++m)
#pragma unroll
      for (int rr = 0; rr < 4; ++rr) {
        const long row = row0 + m * 16 + rr;
#pragma unroll
        for (int n = 0; n < 4; ++n)
          Cc[row * N + col0 + n * 16] = f2bf(acc[m][n][rr]);
      }
  } else {
    float* Cf = (float*)C;
    float bv[4];
#pragma unroll
    for (int n = 0; n < 4; ++n) bv[n] = bias[col0 + n * 16];
#pragma unroll
    for (int m = 0; m < 8; ++m)
#pragma unroll
      for (int rr = 0; rr < 4; ++rr) {
        const long row = row0 + m * 16 + rr;
#pragma unroll
        for (int n = 0; n < 4; ++n)
          Cf[row * N + col0 + n * 16] = acc[m][n][rr] + bv[n];
      }
  }
}

// ---------------- fused attention (v3: bf16 SB -> 5 blocks/CU) ----------
// one block (256 thr, 4 waves) per (b,h). N=49 padded to 64, hd=64.
// T14 async prev/bias (registers stay in flight across QK^T), coalesced
// attn_out via Ks repack. SB stored as bf16: LDS 37.4 -> 32.5 KB, so
// occupancy rises 4 -> 5 blocks/CU. Softmax still consumes the f32 score
// (only prev+bias staging and the out1 values see one bf16 rounding).
__global__ __launch_bounds__(256) void attn_kernel(
    const u16* __restrict__ qkv,        // [B*49, 2304] bf16
    const float* __restrict__ prev,     // [B,12,49,49]
    const float* __restrict__ biasM,    // [12,49*49]
    float* __restrict__ prev_out,       // [B,12,49,49]
    u16* __restrict__ attn_out) {       // [B*49, 768] bf16
  __shared__ u16 Qs[64][72];   // aliased as Ps after QK^T
  __shared__ u16 Ks[64][72];   // aliased as O-repack after PV
  __shared__ u16 VTs[64][72];
  __shared__ u16 SB[2432];     // prev+bias then scores, bf16

  const int bh = blockIdx.x;
  const int b = bh / 12, h = bh % 12;
  const int t = threadIdx.x, w = t >> 6, l = t & 63, lr = l & 15, lhi = l >> 4;

  // ---- stage Q,K,V^T into LDS ----
  const u16* base = qkv + (long)(b * 49) * 2304 + h * 64;
  for (int idx = t; idx < 49 * 16; idx += 256) {
    const int n = idx >> 4, c4 = (idx & 15) << 2;
    const u16* rp = base + (long)n * 2304;
    ushort4 qv = *(const ushort4*)(rp + c4);
    ushort4 kv = *(const ushort4*)(rp + 768 + c4);
    ushort4 vv = *(const ushort4*)(rp + 1536 + c4);
    *(ushort4*)&Qs[n][c4] = qv;
    *(ushort4*)&Ks[n][c4] = kv;
    VTs[c4 + 0][n] = vv.x;
    VTs[c4 + 1][n] = vv.y;
    VTs[c4 + 2][n] = vv.z;
    VTs[c4 + 3][n] = vv.w;
  }
  for (int idx = t; idx < 1024; idx += 256) {
    const int j = idx & 15;
    if (j) VTs[idx >> 4][48 + j] = 0;
  }

  // ---- issue prev/bias to registers (in flight across QK^T) ----
  float prevR[10], biasR[10];
  {
    const float* pv = prev + (long)bh * 2401;
    const float* bm = biasM + h * 2401;
#pragma unroll
    for (int k = 0; k < 10; ++k) {
      const int i = t + 256 * k;
      if (i < 2401) {
        prevR[k] = pv[i];
        biasR[k] = bm[i];
      }
    }
  }

  // raw barrier: drain only LDS writes; vmcnt (prev/bias) stays outstanding
  asm volatile("s_waitcnt lgkmcnt(0)" ::: "memory");
  __builtin_amdgcn_s_barrier();
  asm volatile("" ::: "memory");

  // ---- QK^T ----
  bf16x8 af0 = *(const bf16x8*)&Qs[16 * w + lr][lhi * 8];
  bf16x8 af1 = *(const bf16x8*)&Qs[16 * w + lr][32 + lhi * 8];
  f32x4 sacc[4];
#pragma unroll
  for (int tc = 0; tc < 4; ++tc) {
    sacc[tc] = (f32x4){0.f, 0.f, 0.f, 0.f};
    bf16x8 b0 = *(const bf16x8*)&Ks[16 * tc + lr][lhi * 8];
    bf16x8 b1 = *(const bf16x8*)&Ks[16 * tc + lr][32 + lhi * 8];
    sacc[tc] = __builtin_amdgcn_mfma_f32_16x16x32_bf16(af0, b0, sacc[tc], 0, 0, 0);
    sacc[tc] = __builtin_amdgcn_mfma_f32_16x16x32_bf16(af1, b1, sacc[tc], 0, 0, 0);
  }

  // ---- land prev/bias, build SB (bf16), publish ----
  asm volatile("s_waitcnt vmcnt(0)" ::: "memory");
#pragma unroll
  for (int k = 0; k < 10; ++k) {
    const int i = t + 256 * k;
    if (i < 2401) SB[i] = f2bf(prevR[k] + biasR[k]);
  }
  asm volatile("s_waitcnt lgkmcnt(0)" ::: "memory");
  __builtin_amdgcn_s_barrier();
  asm volatile("" ::: "memory");

  // ---- epilogue + softmax (f32 score; SB stores bf16 for out1) ----
  u16 (*Ps)[72] = Qs;  // alias: wave w reads only its own Q rows before writing
  const int nrow0 = 16 * w + 4 * lhi;
  float rs[4];
#pragma unroll
  for (int r = 0; r < 4; ++r) {
    const int row = nrow0 + r;
    const bool rv = row < 49;
    float sv[4];
#pragma unroll
    for (int tc = 0; tc < 4; ++tc) {
      const int col = 16 * tc + lr;
      const bool valid = rv && (col < 49);
      const int sidx = (row < 49 ? row : 48) * 49 + (col < 49 ? col : 48);
      const float pb = bf2f(SB[sidx]);
      const float s = sacc[tc][r] * 0.125f + pb;
      if (valid) SB[sidx] = f2bf(s);
      sv[tc] = valid ? s : -INFINITY;
    }
    float mx = fmaxf(fmaxf(sv[0], sv[1]), fmaxf(sv[2], sv[3]));
#pragma unroll
    for (int off = 8; off; off >>= 1) mx = fmaxf(mx, __shfl_xor(mx, off, 16));
    float e[4], sum = 0.f;
#pragma unroll
    for (int tc = 0; tc < 4; ++tc) {
      e[tc] = __expf(sv[tc] - mx);
      sum += e[tc];
    }
#pragma unroll
    for (int off = 8; off; off >>= 1) sum += __shfl_xor(sum, off, 16);
    rs[r] = 1.0f / sum;
#pragma unroll
    for (int tc = 0; tc < 4; ++tc)
      Ps[row][16 * tc + lr] = rv ? f2bf(e[tc]) : (u16)0;
  }
  __syncthreads();

  // ---- P*V ----
  bf16x8 pf0 = *(const bf16x8*)&Ps[16 * w + lr][lhi * 8];
  bf16x8 pf1 = *(const bf16x8*)&Ps[16 * w + lr][32 + lhi * 8];
  f32x4 oacc[4];
#pragma unroll
  for (int dc = 0; dc < 4; ++dc) {
    oacc[dc] = (f32x4){0.f, 0.f, 0.f, 0.f};
    bf16x8 v0 = *(const bf16x8*)&VTs[16 * dc + lr][lhi * 8];
    bf16x8 v1 = *(const bf16x8*)&VTs[16 * dc + lr][32 + lhi * 8];
    oacc[dc] = __builtin_amdgcn_mfma_f32_16x16x32_bf16(pf0, v0, oacc[dc], 0, 0, 0);
    oacc[dc] = __builtin_amdgcn_mfma_f32_16x16x32_bf16(pf1, v1, oacc[dc], 0, 0, 0);
  }

  // ---- repack O into Ks (free after QK^T) for coalesced writes ----
#pragma unroll
  for (int r = 0; r < 4; ++r) {
    const int row = nrow0 + r;
    if (row < 49) {
#pragma unroll
      for (int dc = 0; dc < 4; ++dc)
        Ks[row][16 * dc + lr] = f2bf(oacc[dc][r] * rs[r]);
    }
  }
  __syncthreads();

  // ---- stream attn_out (128B rows via dwordx4) + prev_out ----
  {
    u16* ob = attn_out + (long)(b * 49) * 768 + h * 64;
    for (int idx = t; idx < 49 * 8; idx += 256) {
      const int row = idx >> 3, cc = (idx & 7) << 3;
      *(ulonglong2*)&ob[(long)row * 768 + cc] = *(const ulonglong2*)&Ks[row][cc];
    }
    float* pout = prev_out + (long)bh * 2401;
    for (int i = t; i < 2401; i += 256) pout[i] = bf2f(SB[i]);
  }
}

// ---------------- launch ----------------
extern "C" void kernel_launch(void* const* d_in, const int* in_sizes, int n_in,
                              void* d_out, int out_size, void* d_ws, size_t ws_size,
                              hipStream_t stream) {
  const float* x = (const float*)d_in[0];
  const float* prev = (const float*)d_in[1];
  const float* qkv_w = (const float*)d_in[2];
  const float* proj_w = (const float*)d_in[3];
  const float* proj_b = (const float*)d_in[4];
  const float* bias_table = (const float*)d_in[5];
  const int* rel_idx = (const int*)d_in[6];

  const int B = in_sizes[0] / (49 * 768);  // 1024
  const int M = B * 49;                    // 50176 = 196*256

  float* out0 = (float*)d_out;             // [M,768]
  float* out1 = out0 + (size_t)M * 768;    // [B,12,49,49]

  char* ws = (char*)d_ws;
  u16* xbf = (u16*)ws;                                     // M*768 bf16 (reused as attn_out)
  u16* qkvbf = (u16*)(ws + (size_t)M * 768 * 2);           // M*2304 bf16
  u16* qkvwT = (u16*)(ws + (size_t)M * 768 * 2 + (size_t)M * 2304 * 2);  // [2304,768]
  u16* projwT = qkvwT + 2304 * 768;                        // [768,768]
  float* biasM = (float*)(projwT + 768 * 768);             // [12,2401]

  bias_pre<<<(12 * 2401 + 255) / 256, 256, 0, stream>>>(bias_table, rel_idx, biasM);
  cvt_bf16<<<2048, 256, 0, stream>>>(x, xbf, M * 768 / 4);
  cvtT_bf16<<<(2304 * 768 + 255) / 256, 256, 0, stream>>>(qkv_w, qkvwT, 768, 2304);
  cvtT_bf16<<<(768 * 768 + 255) / 256, 256, 0, stream>>>(proj_w, projwT, 768, 768);

  gemm256<true><<<(M / 256) * (2304 / 256), 512, 0, stream>>>(
      xbf, qkvwT, qkvbf, nullptr, M, 2304, 768, 2304 / 256);

  attn_kernel<<<B * 12, 256, 0, stream>>>(qkvbf, prev, biasM, out1, xbf);

  gemm256<false><<<(M / 256) * (768 / 256), 512, 0, stream>>>(
      xbf, projwT, out0, proj_b, M, 768, 768, 768 / 256);
}

// Round 12
// 471.150 us; speedup vs baseline: 1.0097x; 1.0097x over previous
//
#include <hip/hip_runtime.h>

typedef unsigned short u16;
typedef unsigned int u32;
typedef float f32x4 __attribute__((ext_vector_type(4)));
typedef __bf16 bf16x8 __attribute__((ext_vector_type(8)));

#define DEV static __device__ __forceinline__

DEV u16 f2bf(float f) {
  u32 u = __builtin_bit_cast(u32, f);
  u += 0x7fffu + ((u >> 16) & 1u);
  return (u16)(u >> 16);
}

DEV float bf2f(u16 v) {
  u32 u = ((u32)v) << 16;
  return __builtin_bit_cast(float, u);
}

DEV void gload_lds16(const void* g, void* l) {
  __builtin_amdgcn_global_load_lds(
      (const __attribute__((address_space(1))) u32*)g,
      (__attribute__((address_space(3))) u32*)l, 16, 0, 0);
}

// ---------------- convert kernels ----------------

__global__ __launch_bounds__(256) void cvt_bf16(const float* __restrict__ in,
                                                u16* __restrict__ out, int n4) {
  int i = blockIdx.x * 256 + threadIdx.x;
  const int stride = gridDim.x * 256;
  for (; i < n4; i += stride) {
    const float4 v = ((const float4*)in)[i];
    ushort4 o;
    o.x = f2bf(v.x); o.y = f2bf(v.y); o.z = f2bf(v.z); o.w = f2bf(v.w);
    ((ushort4*)out)[i] = o;
  }
}

// in [K,N] fp32 -> out [N,K] bf16, LDS-tiled transpose (K,N multiples of 32)
__global__ __launch_bounds__(256) void cvtT_tile(const float* __restrict__ in,
                                                 u16* __restrict__ out, int K, int N) {
  __shared__ float tile[32][33];
  const int nbx = N >> 5;
  const int bx = blockIdx.x % nbx, by = blockIdx.x / nbx;
  const int tx = threadIdx.x & 31, ty = threadIdx.x >> 5;  // 32 x 8
  const int gcol = bx * 32 + tx;
#pragma unroll
  for (int j = 0; j < 4; ++j) {
    const int r = ty + 8 * j;
    tile[r][tx] = in[(long)(by * 32 + r) * N + gcol];
  }
  __syncthreads();
#pragma unroll
  for (int j = 0; j < 4; ++j) {
    const int r = ty + 8 * j;  // local n
    out[(long)(bx * 32 + r) * K + by * 32 + tx] = f2bf(tile[tx][r]);
  }
}

// biasM[h][p] = bias_table[rel_idx[p]*12 + h], p < 2401
__global__ __launch_bounds__(256) void bias_pre(const float* __restrict__ bias_table,
                                                const int* __restrict__ rel_idx,
                                                float* __restrict__ biasM) {
  int i = blockIdx.x * 256 + threadIdx.x;
  if (i >= 12 * 2401) return;
  int h = i / 2401, p = i - h * 2401;
  biasM[i] = bias_table[rel_idx[p] * 12 + h];
}

// ---------------- 256x256 GEMM: 5-buffer depth-4 pipeline -----------------
// LDS: 5 buffers x 32KB = 160KB (gfx950 max; AITER uses 160KB too).
// Per-buffer layout + swizzle identical to r6 (conflict-free, measured 0).
// Invariant: at entry of tile kt, tiles <= kt+1 are landed AND published.
// BODY(kt): STAGE(kt+4) into buf(kt-1); afr2 <- tile kt 2nd A-half;
// CLUSTER1; prefetch tile kt+1 B; CLUSTER2; prefetch tile kt+1 A1;
// vmcnt(8) [=> tile kt+2 landed, ~3 tile-times after issue]; barrier.
template <bool OUT_BF16>
__global__ __launch_bounds__(512, 2) void gemm256(
    const u16* __restrict__ A, const u16* __restrict__ BT,
    void* __restrict__ C, const float* __restrict__ bias,
    int M, int N, int K, int nbn) {
  __shared__ alignas(16) char lds[163840];
  const int t = threadIdx.x;
  const int w = t >> 6, l = t & 63, lr = l & 15, lhi = l >> 4;
  const int wr = w >> 2, wc = w & 3;

  // bijective XCD-chunked swizzle
  const int nwg = gridDim.x;
  const int q = nwg >> 3, r = nwg & 7;
  const int xcd = blockIdx.x & 7, lid = blockIdx.x >> 3;
  const int swz = (xcd < r ? xcd * (q + 1) : r * (q + 1) + (xcd - r) * q) + lid;
  const int bm = swz / nbn, bn = swz % nbn;

  const int T = K >> 5;  // K-tiles of 32 (K=768 -> 24, even)
  const long Kb = (long)K * 2;

  // staging source (inverse swizzle; global_load_lds dest is linear)
  const int unswz = (l & 7) ^ (l >> 3);
  const int arow = 2 * (l >> 3) + (unswz >> 2);
  const int acolb = (unswz & 3) << 4;
  const char* gA0 = (const char*)A + (long)(bm * 256 + w * 32 + arow) * Kb + acolb;
  const char* gA1 = gA0 + 16 * Kb;
  const char* gB0 = (const char*)BT + (long)(bn * 256 + w * 32 + arow) * Kb + acolb;
  const char* gB1 = gB0 + 16 * Kb;
  const int ldA0 = w * 2048, ldA1 = w * 2048 + 1024;
  const int ldB0 = 16384 + w * 2048, ldB1 = 16384 + w * 2048 + 1024;

#define STAGE(tt, bb)                           \
  {                                             \
    const long ko = (long)(tt) * 64;            \
    gload_lds16(gA0 + ko, lds + (bb) + ldA0);   \
    gload_lds16(gA1 + ko, lds + (bb) + ldA1);   \
    gload_lds16(gB0 + ko, lds + (bb) + ldB0);   \
    gload_lds16(gB1 + ko, lds + (bb) + ldB1);   \
  }
#define BAR                                  \
  asm volatile("" ::: "memory");             \
  __builtin_amdgcn_s_barrier();              \
  asm volatile("" ::: "memory")

  // frag read offsets (swizzled)
  const int rblk = ((((lr & 1) << 2) | lhi) ^ (lr >> 1));
  const int aoff0 = (wr * 64 + (lr >> 1)) * 128 + rblk * 16;          // + mt*1024
  const int boff0 = 16384 + (wc * 32 + (lr >> 1)) * 128 + rblk * 16;  // + nt*1024

  f32x4 acc[8][4];
#pragma unroll
  for (int m = 0; m < 8; ++m)
#pragma unroll
    for (int n = 0; n < 4; ++n) acc[m][n] = (f32x4){0.f, 0.f, 0.f, 0.f};
  bf16x8 afrX[4], bfrX[4], afrY[4], bfrY[4];

#define CLUSTER1(S)                                                        \
  __builtin_amdgcn_s_setprio(1);                                           \
  _Pragma("unroll") for (int m = 0; m < 4; ++m)                            \
      _Pragma("unroll") for (int n = 0; n < 4; ++n)                        \
          acc[m][n] = __builtin_amdgcn_mfma_f32_16x16x32_bf16(             \
              afr##S[m], bfr##S[n], acc[m][n], 0, 0, 0);                   \
  __builtin_amdgcn_s_setprio(0)
#define CLUSTER2(S)                                                        \
  __builtin_amdgcn_s_setprio(1);                                           \
  _Pragma("unroll") for (int m = 0; m < 4; ++m)                            \
      _Pragma("unroll") for (int n = 0; n < 4; ++n)                        \
          acc[m + 4][n] = __builtin_amdgcn_mfma_f32_16x16x32_bf16(         \
              afr2[m], bfr##S[n], acc[m + 4][n], 0, 0, 0);                 \
  __builtin_amdgcn_s_setprio(0)

// bb0 = LDS offset of buf(kt); rolls 0,32768,...,131072 with period 5.
#define BODY(kt, S, R)                                                     \
  {                                                                        \
    int sbb = bb0 - 32768; if (sbb < 0) sbb = 131072;   /* buf(kt-1) */    \
    int nbb = bb0 + 32768; if (nbb > 131072) nbb = 0;   /* buf(kt+1) */    \
    if ((kt) + 4 < T) STAGE((kt) + 4, sbb);                                \
    bf16x8 afr2[4];                                                        \
    _Pragma("unroll") for (int m = 0; m < 4; ++m)                          \
        afr2[m] = *(const bf16x8*)(lds + bb0 + aoff0 + (m + 4) * 1024);    \
    CLUSTER1(S);                                                           \
    const int rb = ((kt) + 1 < T) ? nbb : bb0;                             \
    _Pragma("unroll") for (int n = 0; n < 4; ++n)                          \
        bfr##R[n] = *(const bf16x8*)(lds + rb + boff0 + n * 1024);         \
    CLUSTER2(S);                                                           \
    _Pragma("unroll") for (int m = 0; m < 4; ++m)                          \
        afr##R[m] = *(const bf16x8*)(lds + rb + aoff0 + m * 1024);         \
    if ((kt) + 4 < T) {                                                    \
      asm volatile("s_waitcnt vmcnt(8)" ::: "memory");                     \
    } else if ((kt) + 3 < T) {                                             \
      asm volatile("s_waitcnt vmcnt(4)" ::: "memory");                     \
    } else {                                                               \
      asm volatile("s_waitcnt vmcnt(0)" ::: "memory");                     \
    }                                                                      \
    BAR;                                                                   \
    bb0 = nbb;                                                             \
  }

  // prologue: stage tiles 0..3 into bufs 0..3; vmcnt(8) -> tiles 0,1 landed.
  STAGE(0, 0); STAGE(1, 32768); STAGE(2, 65536); STAGE(3, 98304);
  asm volatile("s_waitcnt vmcnt(8)" ::: "memory");
  BAR;
  int bb0 = 0;
#pragma unroll
  for (int n = 0; n < 4; ++n) bfrX[n] = *(const bf16x8*)(lds + boff0 + n * 1024);
#pragma unroll
  for (int m = 0; m < 4; ++m) afrX[m] = *(const bf16x8*)(lds + aoff0 + m * 1024);

  for (int i = 0; i < T / 2; ++i) {
    BODY(2 * i, X, Y);
    BODY(2 * i + 1, Y, X);
  }
#undef STAGE
#undef BAR
#undef CLUSTER1
#undef CLUSTER2
#undef BODY

  const int row0 = bm * 256 + wr * 128 + 4 * lhi;
  const int col0 = bn * 256 + wc * 64 + lr;
  if (OUT_BF16) {
    u16* Cc = (u16*)C;
#pragma unroll
    for (int m = 0; m < 8; ++m)
#pragma unroll
      for (int rr = 0; rr < 4; ++rr) {
        const long row = row0 + m * 16 + rr;
#pragma unroll
        for (int n = 0; n < 4; ++n)
          Cc[row * N + col0 + n * 16] = f2bf(acc[m][n][rr]);
      }
  } else {
    float* Cf = (float*)C;
    float bv[4];
#pragma unroll
    for (int n = 0; n < 4; ++n) bv[n] = bias[col0 + n * 16];
#pragma unroll
    for (int m = 0; m < 8; ++m)
#pragma unroll
      for (int rr = 0; rr < 4; ++rr) {
        const long row = row0 + m * 16 + rr;
#pragma unroll
        for (int n = 0; n < 4; ++n)
          Cf[row * N + col0 + n * 16] = acc[m][n][rr] + bv[n];
      }
  }
}

// ---------------- fused attention (r11: T14 async + bf16 SB + coalesced out)
__global__ __launch_bounds__(256) void attn_kernel(
    const u16* __restrict__ qkv,        // [B*49, 2304] bf16
    const float* __restrict__ prev,     // [B,12,49,49]
    const float* __restrict__ biasM,    // [12,49*49]
    float* __restrict__ prev_out,       // [B,12,49,49]
    u16* __restrict__ attn_out) {       // [B*49, 768] bf16
  __shared__ u16 Qs[64][72];   // aliased as Ps after QK^T
  __shared__ u16 Ks[64][72];   // aliased as O-repack after PV
  __shared__ u16 VTs[64][72];
  __shared__ u16 SB[2432];     // prev+bias then scores, bf16

  const int bh = blockIdx.x;
  const int b = bh / 12, h = bh % 12;
  const int t = threadIdx.x, w = t >> 6, l = t & 63, lr = l & 15, lhi = l >> 4;

  const u16* base = qkv + (long)(b * 49) * 2304 + h * 64;
  for (int idx = t; idx < 49 * 16; idx += 256) {
    const int n = idx >> 4, c4 = (idx & 15) << 2;
    const u16* rp = base + (long)n * 2304;
    ushort4 qv = *(const ushort4*)(rp + c4);
    ushort4 kv = *(const ushort4*)(rp + 768 + c4);
    ushort4 vv = *(const ushort4*)(rp + 1536 + c4);
    *(ushort4*)&Qs[n][c4] = qv;
    *(ushort4*)&Ks[n][c4] = kv;
    VTs[c4 + 0][n] = vv.x;
    VTs[c4 + 1][n] = vv.y;
    VTs[c4 + 2][n] = vv.z;
    VTs[c4 + 3][n] = vv.w;
  }
  for (int idx = t; idx < 1024; idx += 256) {
    const int j = idx & 15;
    if (j) VTs[idx >> 4][48 + j] = 0;
  }

  float prevR[10], biasR[10];
  {
    const float* pv = prev + (long)bh * 2401;
    const float* bm = biasM + h * 2401;
#pragma unroll
    for (int k = 0; k < 10; ++k) {
      const int i = t + 256 * k;
      if (i < 2401) {
        prevR[k] = pv[i];
        biasR[k] = bm[i];
      }
    }
  }

  asm volatile("s_waitcnt lgkmcnt(0)" ::: "memory");
  __builtin_amdgcn_s_barrier();
  asm volatile("" ::: "memory");

  bf16x8 af0 = *(const bf16x8*)&Qs[16 * w + lr][lhi * 8];
  bf16x8 af1 = *(const bf16x8*)&Qs[16 * w + lr][32 + lhi * 8];
  f32x4 sacc[4];
#pragma unroll
  for (int tc = 0; tc < 4; ++tc) {
    sacc[tc] = (f32x4){0.f, 0.f, 0.f, 0.f};
    bf16x8 b0 = *(const bf16x8*)&Ks[16 * tc + lr][lhi * 8];
    bf16x8 b1 = *(const bf16x8*)&Ks[16 * tc + lr][32 + lhi * 8];
    sacc[tc] = __builtin_amdgcn_mfma_f32_16x16x32_bf16(af0, b0, sacc[tc], 0, 0, 0);
    sacc[tc] = __builtin_amdgcn_mfma_f32_16x16x32_bf16(af1, b1, sacc[tc], 0, 0, 0);
  }

  asm volatile("s_waitcnt vmcnt(0)" ::: "memory");
#pragma unroll
  for (int k = 0; k < 10; ++k) {
    const int i = t + 256 * k;
    if (i < 2401) SB[i] = f2bf(prevR[k] + biasR[k]);
  }
  asm volatile("s_waitcnt lgkmcnt(0)" ::: "memory");
  __builtin_amdgcn_s_barrier();
  asm volatile("" ::: "memory");

  u16 (*Ps)[72] = Qs;
  const int nrow0 = 16 * w + 4 * lhi;
  float rs[4];
#pragma unroll
  for (int r = 0; r < 4; ++r) {
    const int row = nrow0 + r;
    const bool rv = row < 49;
    float sv[4];
#pragma unroll
    for (int tc = 0; tc < 4; ++tc) {
      const int col = 16 * tc + lr;
      const bool valid = rv && (col < 49);
      const int sidx = (row < 49 ? row : 48) * 49 + (col < 49 ? col : 48);
      const float pb = bf2f(SB[sidx]);
      const float s = sacc[tc][r] * 0.125f + pb;
      if (valid) SB[sidx] = f2bf(s);
      sv[tc] = valid ? s : -INFINITY;
    }
    float mx = fmaxf(fmaxf(sv[0], sv[1]), fmaxf(sv[2], sv[3]));
#pragma unroll
    for (int off = 8; off; off >>= 1) mx = fmaxf(mx, __shfl_xor(mx, off, 16));
    float e[4], sum = 0.f;
#pragma unroll
    for (int tc = 0; tc < 4; ++tc) {
      e[tc] = __expf(sv[tc] - mx);
      sum += e[tc];
    }
#pragma unroll
    for (int off = 8; off; off >>= 1) sum += __shfl_xor(sum, off, 16);
    rs[r] = 1.0f / sum;
#pragma unroll
    for (int tc = 0; tc < 4; ++tc)
      Ps[row][16 * tc + lr] = rv ? f2bf(e[tc]) : (u16)0;
  }
  __syncthreads();

  bf16x8 pf0 = *(const bf16x8*)&Ps[16 * w + lr][lhi * 8];
  bf16x8 pf1 = *(const bf16x8*)&Ps[16 * w + lr][32 + lhi * 8];
  f32x4 oacc[4];
#pragma unroll
  for (int dc = 0; dc < 4; ++dc) {
    oacc[dc] = (f32x4){0.f, 0.f, 0.f, 0.f};
    bf16x8 v0 = *(const bf16x8*)&VTs[16 * dc + lr][lhi * 8];
    bf16x8 v1 = *(const bf16x8*)&VTs[16 * dc + lr][32 + lhi * 8];
    oacc[dc] = __builtin_amdgcn_mfma_f32_16x16x32_bf16(pf0, v0, oacc[dc], 0, 0, 0);
    oacc[dc] = __builtin_amdgcn_mfma_f32_16x16x32_bf16(pf1, v1, oacc[dc], 0, 0, 0);
  }

#pragma unroll
  for (int r = 0; r < 4; ++r) {
    const int row = nrow0 + r;
    if (row < 49) {
#pragma unroll
      for (int dc = 0; dc < 4; ++dc)
        Ks[row][16 * dc + lr] = f2bf(oacc[dc][r] * rs[r]);
    }
  }
  __syncthreads();

  {
    u16* ob = attn_out + (long)(b * 49) * 768 + h * 64;
    for (int idx = t; idx < 49 * 8; idx += 256) {
      const int row = idx >> 3, cc = (idx & 7) << 3;
      *(ulonglong2*)&ob[(long)row * 768 + cc] = *(const ulonglong2*)&Ks[row][cc];
    }
    float* pout = prev_out + (long)bh * 2401;
    for (int i = t; i < 2401; i += 256) pout[i] = bf2f(SB[i]);
  }
}

// ---------------- launch ----------------
extern "C" void kernel_launch(void* const* d_in, const int* in_sizes, int n_in,
                              void* d_out, int out_size, void* d_ws, size_t ws_size,
                              hipStream_t stream) {
  const float* x = (const float*)d_in[0];
  const float* prev = (const float*)d_in[1];
  const float* qkv_w = (const float*)d_in[2];
  const float* proj_w = (const float*)d_in[3];
  const float* proj_b = (const float*)d_in[4];
  const float* bias_table = (const float*)d_in[5];
  const int* rel_idx = (const int*)d_in[6];

  const int B = in_sizes[0] / (49 * 768);  // 1024
  const int M = B * 49;                    // 50176 = 196*256

  float* out0 = (float*)d_out;             // [M,768]
  float* out1 = out0 + (size_t)M * 768;    // [B,12,49,49]

  char* ws = (char*)d_ws;
  u16* xbf = (u16*)ws;                                     // M*768 bf16 (reused as attn_out)
  u16* qkvbf = (u16*)(ws + (size_t)M * 768 * 2);           // M*2304 bf16
  u16* qkvwT = (u16*)(ws + (size_t)M * 768 * 2 + (size_t)M * 2304 * 2);  // [2304,768]
  u16* projwT = qkvwT + 2304 * 768;                        // [768,768]
  float* biasM = (float*)(projwT + 768 * 768);             // [12,2401]

  bias_pre<<<(12 * 2401 + 255) / 256, 256, 0, stream>>>(bias_table, rel_idx, biasM);
  cvt_bf16<<<2048, 256, 0, stream>>>(x, xbf, M * 768 / 4);
  cvtT_tile<<<(2304 / 32) * (768 / 32), 256, 0, stream>>>(qkv_w, qkvwT, 768, 2304);
  cvtT_tile<<<(768 / 32) * (768 / 32), 256, 0, stream>>>(proj_w, projwT, 768, 768);

  gemm256<true><<<(M / 256) * (2304 / 256), 512, 0, stream>>>(
      xbf, qkvwT, qkvbf, nullptr, M, 2304, 768, 2304 / 256);

  attn_kernel<<<B * 12, 256, 0, stream>>>(qkvbf, prev, biasM, out1, xbf);

  gemm256<false><<<(M / 256) * (768 / 256), 512, 0, stream>>>(
      xbf, projwT, out0, proj_b, M, 768, 768, 768 / 256);
}

// Round 13
// 468.102 us; speedup vs baseline: 1.0163x; 1.0065x over previous
//
#include <hip/hip_runtime.h>

typedef unsigned short u16;
typedef unsigned int u32;
typedef float f32x4 __attribute__((ext_vector_type(4)));
typedef __bf16 bf16x8 __attribute__((ext_vector_type(8)));

#define DEV static __device__ __forceinline__

DEV u16 f2bf(float f) {
  u32 u = __builtin_bit_cast(u32, f);
  u += 0x7fffu + ((u >> 16) & 1u);
  return (u16)(u >> 16);
}

DEV float bf2f(u16 v) {
  u32 u = ((u32)v) << 16;
  return __builtin_bit_cast(float, u);
}

DEV void gload_lds16(const void* g, void* l) {
  __builtin_amdgcn_global_load_lds(
      (const __attribute__((address_space(1))) u32*)g,
      (__attribute__((address_space(3))) u32*)l, 16, 0, 0);
}

// ---------------- convert kernels ----------------

__global__ __launch_bounds__(256) void cvt_bf16(const float* __restrict__ in,
                                                u16* __restrict__ out, int n4) {
  int i = blockIdx.x * 256 + threadIdx.x;
  const int stride = gridDim.x * 256;
  for (; i < n4; i += stride) {
    const float4 v = ((const float4*)in)[i];
    ushort4 o;
    o.x = f2bf(v.x); o.y = f2bf(v.y); o.z = f2bf(v.z); o.w = f2bf(v.w);
    ((ushort4*)out)[i] = o;
  }
}

// in [K,N] fp32 -> out [N,K] bf16, LDS-tiled transpose
__global__ __launch_bounds__(256) void cvtT_tile(const float* __restrict__ in,
                                                 u16* __restrict__ out, int K, int N) {
  __shared__ float tile[32][33];
  const int nbx = N >> 5;
  const int bx = blockIdx.x % nbx, by = blockIdx.x / nbx;
  const int tx = threadIdx.x & 31, ty = threadIdx.x >> 5;  // 32 x 8
  const int gcol = bx * 32 + tx;
#pragma unroll
  for (int j = 0; j < 4; ++j) {
    const int r = ty + 8 * j;
    tile[r][tx] = in[(long)(by * 32 + r) * N + gcol];
  }
  __syncthreads();
#pragma unroll
  for (int j = 0; j < 4; ++j) {
    const int r = ty + 8 * j;
    out[(long)(bx * 32 + r) * K + by * 32 + tx] = f2bf(tile[tx][r]);
  }
}

// biasM[h][p] = bias_table[rel_idx[p]*12 + h], p < 2401
__global__ __launch_bounds__(256) void bias_pre(const float* __restrict__ bias_table,
                                                const int* __restrict__ rel_idx,
                                                float* __restrict__ biasM) {
  int i = blockIdx.x * 256 + threadIdx.x;
  if (i >= 12 * 2401) return;
  int h = i / 2401, p = i - h * 2401;
  biasM[i] = bias_table[rel_idx[p] * 12 + h];
}

// ---------------- 256x256 8-phase GEMM (m201 template port) ----------------
// BK=64, 2 dbuf x 64KB (A[256][64]@0, B[256][64]@32768 per buf).
// Row = 128B, slot' = slot ^ (row&7) swizzle (r8: conflicts == 0, refcheck'd).
// Per K-step t: 4 phases, each {ds_reads + half-stages; BAR; lgkm0+SB;
// setprio1; 16 MFMA (one C-quadrant x K=64); setprio0; BAR}.
// Stage slots: p0: A1(t+1) [other buf]; p2: B0(t+2); p3: B1(t+2)+A0(t+2)
// [current buf, after regions' last reads]. vmcnt(6) once per K-step at p3
// => all of t+1 landed (prologue = 4 halves + 3 halves, matching template).
template <bool OUT_BF16>
__global__ __launch_bounds__(512, 2) void gemm256(
    const u16* __restrict__ A, const u16* __restrict__ BT,
    void* __restrict__ C, const float* __restrict__ bias,
    int M, int N, int K, int nbn) {
  __shared__ alignas(16) char lds[131072];
  const int t = threadIdx.x;
  const int w = t >> 6, l = t & 63, lr = l & 15, lhi = l >> 4;
  const int wr = w >> 2, wc = w & 3;

  // bijective XCD-chunked swizzle
  const int nwg = gridDim.x;
  const int q = nwg >> 3, r = nwg & 7;
  const int xcd = blockIdx.x & 7, lid = blockIdx.x >> 3;
  const int swz = (xcd < r ? xcd * (q + 1) : r * (q + 1) + (xcd - r) * q) + lid;
  const int bm = swz / nbn, bn = swz % nbn;

  const int T = K >> 6;  // BK=64 -> 12 K-steps
  const long Kb = (long)K * 2;

  // staging source (inverse swizzle; global_load_lds dest is linear) — r8's map
  const int srow = w * 16 + (l >> 3);
  const int sb = (l & 7) ^ ((l >> 3) & 7);
  const char* gAs = (const char*)A + (long)(bm * 256 + srow) * Kb + sb * 16;
  const char* gBs = (const char*)BT + (long)(bn * 256 + srow) * Kb + sb * 16;
  const int ldw = w * 2048;

#define SA0(tt) { const int bb=((tt)&1)*65536; const long ko=(long)(tt)*128;      \
  gload_lds16(gAs+ko, lds+bb+ldw); gload_lds16(gAs+8*Kb+ko, lds+bb+ldw+1024); }
#define SA1(tt) { const int bb=((tt)&1)*65536; const long ko=(long)(tt)*128;      \
  gload_lds16(gAs+128*Kb+ko, lds+bb+16384+ldw);                                   \
  gload_lds16(gAs+136*Kb+ko, lds+bb+16384+ldw+1024); }
#define SB0(tt) { const int bb=((tt)&1)*65536; const long ko=(long)(tt)*128;      \
  gload_lds16(gBs+ko, lds+bb+32768+ldw); gload_lds16(gBs+8*Kb+ko, lds+bb+32768+ldw+1024); }
#define SB1(tt) { const int bb=((tt)&1)*65536; const long ko=(long)(tt)*128;      \
  gload_lds16(gBs+128*Kb+ko, lds+bb+49152+ldw);                                   \
  gload_lds16(gBs+136*Kb+ko, lds+bb+49152+ldw+1024); }
#define BAR                                  \
  asm volatile("" ::: "memory");             \
  __builtin_amdgcn_s_barrier();              \
  asm volatile("" ::: "memory")
#define LGKM0                                              \
  asm volatile("s_waitcnt lgkmcnt(0)" ::: "memory");       \
  __builtin_amdgcn_sched_barrier(0)
#define MFMA16(AM, AN, AS, BS)                                               \
  __builtin_amdgcn_s_setprio(1);                                             \
  _Pragma("unroll") for (int mt = 0; mt < 4; ++mt)                           \
  _Pragma("unroll") for (int nt = 0; nt < 2; ++nt) {                         \
    acc[mt + AM][nt + AN] = __builtin_amdgcn_mfma_f32_16x16x32_bf16(         \
        AS[mt][0], BS[nt][0], acc[mt + AM][nt + AN], 0, 0, 0);               \
    acc[mt + AM][nt + AN] = __builtin_amdgcn_mfma_f32_16x16x32_bf16(         \
        AS[mt][1], BS[nt][1], acc[mt + AM][nt + AN], 0, 0, 0);               \
  }                                                                          \
  __builtin_amdgcn_s_setprio(0)

  // frag read offsets (swizzled; r8-verified). ks=1 toggles addr bit 6 (^64).
  const int aoffL = (wr * 128 + lr) * 128 + ((lhi ^ (lr & 7)) << 4);
  const int boffL = 32768 + (wc * 64 + lr) * 128 + ((lhi ^ (lr & 7)) << 4);

  f32x4 acc[8][4];
#pragma unroll
  for (int m = 0; m < 8; ++m)
#pragma unroll
    for (int n = 0; n < 4; ++n) acc[m][n] = (f32x4){0.f, 0.f, 0.f, 0.f};

  // prologue: K0's 4 halves, then K1's first 3; vmcnt(6) -> K0 landed.
  SA0(0); SB0(0); SB1(0); SA1(0);
  SB0(1); SB1(1); SA0(1);
  asm volatile("s_waitcnt vmcnt(6)" ::: "memory");
  BAR;

  for (int kt = 0; kt < T; ++kt) {
    const int bb = (kt & 1) * 65536;
    bf16x8 aC[4][2], b0[2][2], b1[2][2];
    // ===== phase 0: reads A(mt0-3)+B(nt0-1); stage A1(kt+1); MFMA (m0,n0) ====
#pragma unroll
    for (int mt = 0; mt < 4; ++mt) {
      aC[mt][0] = *(const bf16x8*)(lds + (bb + aoffL + mt * 2048));
      aC[mt][1] = *(const bf16x8*)(lds + ((bb + aoffL + mt * 2048) ^ 64));
    }
#pragma unroll
    for (int nt = 0; nt < 2; ++nt) {
      b0[nt][0] = *(const bf16x8*)(lds + (bb + boffL + nt * 2048));
      b0[nt][1] = *(const bf16x8*)(lds + ((bb + boffL + nt * 2048) ^ 64));
    }
    if (kt + 1 < T) SA1(kt + 1);
    asm volatile("s_waitcnt lgkmcnt(8)" ::: "memory");
    BAR;
    LGKM0;
    MFMA16(0, 0, aC, b0);
    BAR;
    // ===== phase 1: reads B(nt2-3); MFMA (m0,n1) ====
#pragma unroll
    for (int nt = 0; nt < 2; ++nt) {
      b1[nt][0] = *(const bf16x8*)(lds + (bb + boffL + (nt + 2) * 2048));
      b1[nt][1] = *(const bf16x8*)(lds + ((bb + boffL + (nt + 2) * 2048) ^ 64));
    }
    BAR;
    LGKM0;
    MFMA16(0, 2, aC, b1);
    BAR;
    // ===== phase 2: reads A(mt4-7); stage B0(kt+2); MFMA (m1,n1) ====
#pragma unroll
    for (int mt = 0; mt < 4; ++mt) {
      aC[mt][0] = *(const bf16x8*)(lds + (bb + aoffL + (mt + 4) * 2048));
      aC[mt][1] = *(const bf16x8*)(lds + ((bb + aoffL + (mt + 4) * 2048) ^ 64));
    }
    if (kt + 2 < T) SB0(kt + 2);
    BAR;
    LGKM0;
    MFMA16(4, 2, aC, b1);
    BAR;
    // ===== phase 3: stage B1(kt+2)+A0(kt+2); MFMA (m1,n0); vmcnt ====
    if (kt + 2 < T) { SB1(kt + 2); SA0(kt + 2); }
    BAR;
    LGKM0;
    MFMA16(4, 0, aC, b0);
    if (kt + 3 <= T) {
      asm volatile("s_waitcnt vmcnt(6)" ::: "memory");
    } else {
      asm volatile("s_waitcnt vmcnt(0)" ::: "memory");
    }
    BAR;
  }
#undef SA0
#undef SA1
#undef SB0
#undef SB1
#undef BAR
#undef LGKM0
#undef MFMA16

  const int row0 = bm * 256 + wr * 128 + 4 * lhi;
  const int col0 = bn * 256 + wc * 64 + lr;
  if (OUT_BF16) {
    u16* Cc = (u16*)C;
#pragma unroll
    for (int m = 0; m < 8; ++m)
#pragma unroll
      for (int rr = 0; rr < 4; ++rr) {
        const long row = row0 + m * 16 + rr;
#pragma unroll
        for (int n = 0; n < 4; ++n)
          Cc[row * N + col0 + n * 16] = f2bf(acc[m][n][rr]);
      }
  } else {
    float* Cf = (float*)C;
    float bv[4];
#pragma unroll
    for (int n = 0; n < 4; ++n) bv[n] = bias[col0 + n * 16];
#pragma unroll
    for (int m = 0; m < 8; ++m)
#pragma unroll
      for (int rr = 0; rr < 4; ++rr) {
        const long row = row0 + m * 16 + rr;
#pragma unroll
        for (int n = 0; n < 4; ++n)
          Cf[row * N + col0 + n * 16] = acc[m][n][rr] + bv[n];
      }
  }
}

// ---------------- fused attention (r11: T14 async + bf16 SB + coalesced out)
__global__ __launch_bounds__(256) void attn_kernel(
    const u16* __restrict__ qkv,        // [B*49, 2304] bf16
    const float* __restrict__ prev,     // [B,12,49,49]
    const float* __restrict__ biasM,    // [12,49*49]
    float* __restrict__ prev_out,       // [B,12,49,49]
    u16* __restrict__ attn_out) {       // [B*49, 768] bf16
  __shared__ u16 Qs[64][72];   // aliased as Ps after QK^T
  __shared__ u16 Ks[64][72];   // aliased as O-repack after PV
  __shared__ u16 VTs[64][72];
  __shared__ u16 SB[2432];     // prev+bias then scores, bf16

  const int bh = blockIdx.x;
  const int b = bh / 12, h = bh % 12;
  const int t = threadIdx.x, w = t >> 6, l = t & 63, lr = l & 15, lhi = l >> 4;

  const u16* base = qkv + (long)(b * 49) * 2304 + h * 64;
  for (int idx = t; idx < 49 * 16; idx += 256) {
    const int n = idx >> 4, c4 = (idx & 15) << 2;
    const u16* rp = base + (long)n * 2304;
    ushort4 qv = *(const ushort4*)(rp + c4);
    ushort4 kv = *(const ushort4*)(rp + 768 + c4);
    ushort4 vv = *(const ushort4*)(rp + 1536 + c4);
    *(ushort4*)&Qs[n][c4] = qv;
    *(ushort4*)&Ks[n][c4] = kv;
    VTs[c4 + 0][n] = vv.x;
    VTs[c4 + 1][n] = vv.y;
    VTs[c4 + 2][n] = vv.z;
    VTs[c4 + 3][n] = vv.w;
  }
  for (int idx = t; idx < 1024; idx += 256) {
    const int j = idx & 15;
    if (j) VTs[idx >> 4][48 + j] = 0;
  }

  float prevR[10], biasR[10];
  {
    const float* pv = prev + (long)bh * 2401;
    const float* bm = biasM + h * 2401;
#pragma unroll
    for (int k = 0; k < 10; ++k) {
      const int i = t + 256 * k;
      if (i < 2401) {
        prevR[k] = pv[i];
        biasR[k] = bm[i];
      }
    }
  }

  asm volatile("s_waitcnt lgkmcnt(0)" ::: "memory");
  __builtin_amdgcn_s_barrier();
  asm volatile("" ::: "memory");

  bf16x8 af0 = *(const bf16x8*)&Qs[16 * w + lr][lhi * 8];
  bf16x8 af1 = *(const bf16x8*)&Qs[16 * w + lr][32 + lhi * 8];
  f32x4 sacc[4];
#pragma unroll
  for (int tc = 0; tc < 4; ++tc) {
    sacc[tc] = (f32x4){0.f, 0.f, 0.f, 0.f};
    bf16x8 b0 = *(const bf16x8*)&Ks[16 * tc + lr][lhi * 8];
    bf16x8 b1 = *(const bf16x8*)&Ks[16 * tc + lr][32 + lhi * 8];
    sacc[tc] = __builtin_amdgcn_mfma_f32_16x16x32_bf16(af0, b0, sacc[tc], 0, 0, 0);
    sacc[tc] = __builtin_amdgcn_mfma_f32_16x16x32_bf16(af1, b1, sacc[tc], 0, 0, 0);
  }

  asm volatile("s_waitcnt vmcnt(0)" ::: "memory");
#pragma unroll
  for (int k = 0; k < 10; ++k) {
    const int i = t + 256 * k;
    if (i < 2401) SB[i] = f2bf(prevR[k] + biasR[k]);
  }
  asm volatile("s_waitcnt lgkmcnt(0)" ::: "memory");
  __builtin_amdgcn_s_barrier();
  asm volatile("" ::: "memory");

  u16 (*Ps)[72] = Qs;
  const int nrow0 = 16 * w + 4 * lhi;
  float rs[4];
#pragma unroll
  for (int r = 0; r < 4; ++r) {
    const int row = nrow0 + r;
    const bool rv = row < 49;
    float sv[4];
#pragma unroll
    for (int tc = 0; tc < 4; ++tc) {
      const int col = 16 * tc + lr;
      const bool valid = rv && (col < 49);
      const int sidx = (row < 49 ? row : 48) * 49 + (col < 49 ? col : 48);
      const float pb = bf2f(SB[sidx]);
      const float s = sacc[tc][r] * 0.125f + pb;
      if (valid) SB[sidx] = f2bf(s);
      sv[tc] = valid ? s : -INFINITY;
    }
    float mx = fmaxf(fmaxf(sv[0], sv[1]), fmaxf(sv[2], sv[3]));
#pragma unroll
    for (int off = 8; off; off >>= 1) mx = fmaxf(mx, __shfl_xor(mx, off, 16));
    float e[4], sum = 0.f;
#pragma unroll
    for (int tc = 0; tc < 4; ++tc) {
      e[tc] = __expf(sv[tc] - mx);
      sum += e[tc];
    }
#pragma unroll
    for (int off = 8; off; off >>= 1) sum += __shfl_xor(sum, off, 16);
    rs[r] = 1.0f / sum;
#pragma unroll
    for (int tc = 0; tc < 4; ++tc)
      Ps[row][16 * tc + lr] = rv ? f2bf(e[tc]) : (u16)0;
  }
  __syncthreads();

  bf16x8 pf0 = *(const bf16x8*)&Ps[16 * w + lr][lhi * 8];
  bf16x8 pf1 = *(const bf16x8*)&Ps[16 * w + lr][32 + lhi * 8];
  f32x4 oacc[4];
#pragma unroll
  for (int dc = 0; dc < 4; ++dc) {
    oacc[dc] = (f32x4){0.f, 0.f, 0.f, 0.f};
    bf16x8 v0 = *(const bf16x8*)&VTs[16 * dc + lr][lhi * 8];
    bf16x8 v1 = *(const bf16x8*)&VTs[16 * dc + lr][32 + lhi * 8];
    oacc[dc] = __builtin_amdgcn_mfma_f32_16x16x32_bf16(pf0, v0, oacc[dc], 0, 0, 0);
    oacc[dc] = __builtin_amdgcn_mfma_f32_16x16x32_bf16(pf1, v1, oacc[dc], 0, 0, 0);
  }

#pragma unroll
  for (int r = 0; r < 4; ++r) {
    const int row = nrow0 + r;
    if (row < 49) {
#pragma unroll
      for (int dc = 0; dc < 4; ++dc)
        Ks[row][16 * dc + lr] = f2bf(oacc[dc][r] * rs[r]);
    }
  }
  __syncthreads();

  {
    u16* ob = attn_out + (long)(b * 49) * 768 + h * 64;
    for (int idx = t; idx < 49 * 8; idx += 256) {
      const int row = idx >> 3, cc = (idx & 7) << 3;
      *(ulonglong2*)&ob[(long)row * 768 + cc] = *(const ulonglong2*)&Ks[row][cc];
    }
    float* pout = prev_out + (long)bh * 2401;
    for (int i = t; i < 2401; i += 256) pout[i] = bf2f(SB[i]);
  }
}

// ---------------- launch ----------------
extern "C" void kernel_launch(void* const* d_in, const int* in_sizes, int n_in,
                              void* d_out, int out_size, void* d_ws, size_t ws_size,
                              hipStream_t stream) {
  const float* x = (const float*)d_in[0];
  const float* prev = (const float*)d_in[1];
  const float* qkv_w = (const float*)d_in[2];
  const float* proj_w = (const float*)d_in[3];
  const float* proj_b = (const float*)d_in[4];
  const float* bias_table = (const float*)d_in[5];
  const int* rel_idx = (const int*)d_in[6];

  const int B = in_sizes[0] / (49 * 768);  // 1024
  const int M = B * 49;                    // 50176 = 196*256

  float* out0 = (float*)d_out;             // [M,768]
  float* out1 = out0 + (size_t)M * 768;    // [B,12,49,49]

  char* ws = (char*)d_ws;
  u16* xbf = (u16*)ws;                                     // M*768 bf16 (reused as attn_out)
  u16* qkvbf = (u16*)(ws + (size_t)M * 768 * 2);           // M*2304 bf16
  u16* qkvwT = (u16*)(ws + (size_t)M * 768 * 2 + (size_t)M * 2304 * 2);  // [2304,768]
  u16* projwT = qkvwT + 2304 * 768;                        // [768,768]
  float* biasM = (float*)(projwT + 768 * 768);             // [12,2401]

  bias_pre<<<(12 * 2401 + 255) / 256, 256, 0, stream>>>(bias_table, rel_idx, biasM);
  cvt_bf16<<<2048, 256, 0, stream>>>(x, xbf, M * 768 / 4);
  cvtT_tile<<<(2304 / 32) * (768 / 32), 256, 0, stream>>>(qkv_w, qkvwT, 768, 2304);
  cvtT_tile<<<(768 / 32) * (768 / 32), 256, 0, stream>>>(proj_w, projwT, 768, 768);

  gemm256<true><<<(M / 256) * (2304 / 256), 512, 0, stream>>>(
      xbf, qkvwT, qkvbf, nullptr, M, 2304, 768, 2304 / 256);

  attn_kernel<<<B * 12, 256, 0, stream>>>(qkvbf, prev, biasM, out1, xbf);

  gemm256<false><<<(M / 256) * (768 / 256), 512, 0, stream>>>(
      xbf, projwT, out0, proj_b, M, 768, 768, 768 / 256);
}

// Round 14
// 455.875 us; speedup vs baseline: 1.0435x; 1.0268x over previous
//
#include <hip/hip_runtime.h>

typedef unsigned short u16;
typedef unsigned int u32;
typedef float f32x4 __attribute__((ext_vector_type(4)));
typedef __bf16 bf16x8 __attribute__((ext_vector_type(8)));

#define DEV static __device__ __forceinline__

DEV u16 f2bf(float f) {
  u32 u = __builtin_bit_cast(u32, f);
  u += 0x7fffu + ((u >> 16) & 1u);
  return (u16)(u >> 16);
}

DEV float bf2f(u16 v) {
  u32 u = ((u32)v) << 16;
  return __builtin_bit_cast(float, u);
}

DEV void gload_lds16(const void* g, void* l) {
  __builtin_amdgcn_global_load_lds(
      (const __attribute__((address_space(1))) u32*)g,
      (__attribute__((address_space(3))) u32*)l, 16, 0, 0);
}

// ---------------- fused preprocessing: cvt + 2 transposes + bias gather ----
// blocks [0,2048): x fp32 -> bf16 (grid-stride)
// blocks [2048,3776): qkv_w [768,2304] -> qkvwT [2304,768] (32x33 LDS tile)
// blocks [3776,4352): proj_w [768,768] -> projwT [768,768]
// blocks [4352,4465): biasM[h][p] = bias_table[rel_idx[p]*12+h]
__global__ __launch_bounds__(256) void prep(
    const float* __restrict__ x, u16* __restrict__ xbf, int n4,
    const float* __restrict__ qkv_w, u16* __restrict__ qkvwT,
    const float* __restrict__ proj_w, u16* __restrict__ projwT,
    const float* __restrict__ bias_table, const int* __restrict__ rel_idx,
    float* __restrict__ biasM) {
  __shared__ float tile[32][33];
  const int bid = blockIdx.x;
  if (bid < 2048) {
    int i = bid * 256 + threadIdx.x;
    for (; i < n4; i += 2048 * 256) {
      const float4 v = ((const float4*)x)[i];
      ushort4 o;
      o.x = f2bf(v.x); o.y = f2bf(v.y); o.z = f2bf(v.z); o.w = f2bf(v.w);
      ((ushort4*)xbf)[i] = o;
    }
  } else if (bid < 2048 + 1728 + 576) {
    const bool qk = bid < 2048 + 1728;
    const int b2 = qk ? bid - 2048 : bid - (2048 + 1728);
    const float* in = qk ? qkv_w : proj_w;
    u16* out = qk ? qkvwT : projwT;
    const int N = qk ? 2304 : 768;
    const int nbx = N >> 5;
    const int bx = b2 % nbx, by = b2 / nbx;
    const int tx = threadIdx.x & 31, ty = threadIdx.x >> 5;
#pragma unroll
    for (int j = 0; j < 4; ++j)
      tile[ty + 8 * j][tx] = in[(long)(by * 32 + ty + 8 * j) * N + bx * 32 + tx];
    __syncthreads();
#pragma unroll
    for (int j = 0; j < 4; ++j)
      out[(long)(bx * 32 + ty + 8 * j) * 768 + by * 32 + tx] = f2bf(tile[tx][ty + 8 * j]);
  } else {
    const int i = (bid - (2048 + 1728 + 576)) * 256 + threadIdx.x;
    if (i < 12 * 2401) {
      const int h = i / 2401, p = i - h * 2401;
      biasM[i] = bias_table[rel_idx[p] * 12 + h];
    }
  }
}

// ---------------- 256x256 deep-pipelined GEMM (best measured: r6/r10) ------
// LDS layout (per 32KB buffer): A = 128 lines x 128B (2 m-rows/line), B @+16384.
// Swizzle: (row, 16B-blk b) -> line = row>>1, slot = (row&1)*4+b, slot ^= line&7.
// Conflict-free (measured 0). Depth-3 staging, vmcnt(4) at bottom so tiles
// kt+1,kt+2 are published entering iter kt+1 -> next tile's fragments
// prefetched in-register DURING iter kt (ping-pong X/Y).
template <bool OUT_BF16>
__global__ __launch_bounds__(512, 2) void gemm256(
    const u16* __restrict__ A, const u16* __restrict__ BT,
    void* __restrict__ C, const float* __restrict__ bias,
    int M, int N, int K, int nbn) {
  __shared__ alignas(16) char lds[131072];
  const int t = threadIdx.x;
  const int w = t >> 6, l = t & 63, lr = l & 15, lhi = l >> 4;
  const int wr = w >> 2, wc = w & 3;

  // bijective XCD-chunked swizzle
  const int nwg = gridDim.x;
  const int q = nwg >> 3, r = nwg & 7;
  const int xcd = blockIdx.x & 7, lid = blockIdx.x >> 3;
  const int swz = (xcd < r ? xcd * (q + 1) : r * (q + 1) + (xcd - r) * q) + lid;
  const int bm = swz / nbn, bn = swz % nbn;

  const int T = K >> 5;  // K-tiles of 32 (K=768 -> 24, even)
  const long Kb = (long)K * 2;

  // staging source (inverse swizzle; global_load_lds dest is linear)
  const int unswz = (l & 7) ^ (l >> 3);
  const int arow = 2 * (l >> 3) + (unswz >> 2);
  const int acolb = (unswz & 3) << 4;
  const char* gA0 = (const char*)A + (long)(bm * 256 + w * 32 + arow) * Kb + acolb;
  const char* gA1 = gA0 + 16 * Kb;
  const char* gB0 = (const char*)BT + (long)(bn * 256 + w * 32 + arow) * Kb + acolb;
  const char* gB1 = gB0 + 16 * Kb;
  const int ldA0 = w * 2048, ldA1 = w * 2048 + 1024;
  const int ldB0 = 16384 + w * 2048, ldB1 = 16384 + w * 2048 + 1024;

#define STAGE(tt)                               \
  {                                             \
    const int bb = ((tt) & 3) * 32768;          \
    const long ko = (long)(tt) * 64;            \
    gload_lds16(gA0 + ko, lds + bb + ldA0);     \
    gload_lds16(gA1 + ko, lds + bb + ldA1);     \
    gload_lds16(gB0 + ko, lds + bb + ldB0);     \
    gload_lds16(gB1 + ko, lds + bb + ldB1);     \
  }
#define BAR                                  \
  asm volatile("" ::: "memory");             \
  __builtin_amdgcn_s_barrier();              \
  asm volatile("" ::: "memory")

  // frag read offsets (swizzled)
  const int rblk = ((((lr & 1) << 2) | lhi) ^ (lr >> 1));
  const int aoff0 = (wr * 64 + (lr >> 1)) * 128 + rblk * 16;          // + mt*1024
  const int boff0 = 16384 + (wc * 32 + (lr >> 1)) * 128 + rblk * 16;  // + nt*1024

  f32x4 acc[8][4];
#pragma unroll
  for (int m = 0; m < 8; ++m)
#pragma unroll
    for (int n = 0; n < 4; ++n) acc[m][n] = (f32x4){0.f, 0.f, 0.f, 0.f};
  bf16x8 afrX[4], bfrX[4], afrY[4], bfrY[4];

#define CLUSTER1(S)                                                        \
  __builtin_amdgcn_s_setprio(1);                                           \
  _Pragma("unroll") for (int m = 0; m < 4; ++m)                            \
      _Pragma("unroll") for (int n = 0; n < 4; ++n)                        \
          acc[m][n] = __builtin_amdgcn_mfma_f32_16x16x32_bf16(             \
              afr##S[m], bfr##S[n], acc[m][n], 0, 0, 0);                   \
  __builtin_amdgcn_s_setprio(0)
#define CLUSTER2(S)                                                        \
  __builtin_amdgcn_s_setprio(1);                                           \
  _Pragma("unroll") for (int m = 0; m < 4; ++m)                            \
      _Pragma("unroll") for (int n = 0; n < 4; ++n)                        \
          acc[m + 4][n] = __builtin_amdgcn_mfma_f32_16x16x32_bf16(         \
              afr2[m], bfr##S[n], acc[m + 4][n], 0, 0, 0);                 \
  __builtin_amdgcn_s_setprio(0)

#define BODY(kt, S, R)                                                     \
  {                                                                        \
    if ((kt) + 3 < T) STAGE((kt) + 3);                                     \
    const int bbc = ((kt) & 3) * 32768;                                    \
    const int nx = ((kt) + 1 < T) ? (kt) + 1 : (kt);                       \
    const int bbn = (nx & 3) * 32768;                                      \
    bf16x8 afr2[4];                                                        \
    _Pragma("unroll") for (int m = 0; m < 4; ++m)                          \
        afr2[m] = *(const bf16x8*)(lds + bbc + aoff0 + (m + 4) * 1024);    \
    CLUSTER1(S);                                                           \
    _Pragma("unroll") for (int n = 0; n < 4; ++n)                          \
        bfr##R[n] = *(const bf16x8*)(lds + bbn + boff0 + n * 1024);        \
    CLUSTER2(S);                                                           \
    _Pragma("unroll") for (int m = 0; m < 4; ++m)                          \
        afr##R[m] = *(const bf16x8*)(lds + bbn + aoff0 + m * 1024);        \
    if ((kt) + 3 < T) {                                                    \
      asm volatile("s_waitcnt vmcnt(4)" ::: "memory");                     \
    } else {                                                               \
      asm volatile("s_waitcnt vmcnt(0)" ::: "memory");                     \
    }                                                                      \
    BAR;                                                                   \
  }

  STAGE(0); STAGE(1); STAGE(2);
  asm volatile("s_waitcnt vmcnt(4)" ::: "memory");
  BAR;
#pragma unroll
  for (int n = 0; n < 4; ++n) bfrX[n] = *(const bf16x8*)(lds + boff0 + n * 1024);
#pragma unroll
  for (int m = 0; m < 4; ++m) afrX[m] = *(const bf16x8*)(lds + aoff0 + m * 1024);

  for (int i = 0; i < T / 2; ++i) {
    BODY(2 * i, X, Y);
    BODY(2 * i + 1, Y, X);
  }
#undef STAGE
#undef BAR
#undef CLUSTER1
#undef CLUSTER2
#undef BODY

  const int row0 = bm * 256 + wr * 128 + 4 * lhi;
  const int col0 = bn * 256 + wc * 64 + lr;
  if (OUT_BF16) {
    u16* Cc = (u16*)C;
#pragma unroll
    for (int m = 0; m < 8; ++m)
#pragma unroll
      for (int rr = 0; rr < 4; ++rr) {
        const long row = row0 + m * 16 + rr;
#pragma unroll
        for (int n = 0; n < 4; ++n)
          Cc[row * N + col0 + n * 16] = f2bf(acc[m][n][rr]);
      }
  } else {
    float* Cf = (float*)C;
    float bv[4];
#pragma unroll
    for (int n = 0; n < 4; ++n) bv[n] = bias[col0 + n * 16];
#pragma unroll
    for (int m = 0; m < 8; ++m)
#pragma unroll
      for (int rr = 0; rr < 4; ++rr) {
        const long row = row0 + m * 16 + rr;
#pragma unroll
        for (int n = 0; n < 4; ++n)
          Cf[row * N + col0 + n * 16] = acc[m][n][rr] + bv[n];
      }
  }
}

// ---------------- fused attention (v4: 2 barriers, wave-local epilogue) ----
// one block (256 thr, 4 waves) per (b,h). N=49 padded to 64, hd=64.
// Barrier #1: QKV staged (prev/bias loads stay in flight: T14).
// Barrier #2: SB = prev+bias published (cross-wave fill).
// After that everything is wave-local: softmax writes Ps rows [16w,16w+16)
// (only owner reads), PV consumes pf from own rows, O repacked back INTO Ps
// (dead after pf loads), per-wave streaming of attn_out and prev_out rows.
__global__ __launch_bounds__(256) void attn_kernel(
    const u16* __restrict__ qkv,        // [B*49, 2304] bf16
    const float* __restrict__ prev,     // [B,12,49,49]
    const float* __restrict__ biasM,    // [12,49*49]
    float* __restrict__ prev_out,       // [B,12,49,49]
    u16* __restrict__ attn_out) {       // [B*49, 768] bf16
  __shared__ u16 Qs[64][72];   // Q -> P -> O (all wave-local transitions)
  __shared__ u16 Ks[64][72];
  __shared__ u16 VTs[64][72];
  __shared__ u16 SB[2432];     // prev+bias then scores, bf16

  const int bh = blockIdx.x;
  const int b = bh / 12, h = bh % 12;
  const int t = threadIdx.x, w = t >> 6, l = t & 63, lr = l & 15, lhi = l >> 4;

  // ---- stage Q,K,V^T into LDS ----
  const u16* base = qkv + (long)(b * 49) * 2304 + h * 64;
  for (int idx = t; idx < 49 * 16; idx += 256) {
    const int n = idx >> 4, c4 = (idx & 15) << 2;
    const u16* rp = base + (long)n * 2304;
    ushort4 qv = *(const ushort4*)(rp + c4);
    ushort4 kv = *(const ushort4*)(rp + 768 + c4);
    ushort4 vv = *(const ushort4*)(rp + 1536 + c4);
    *(ushort4*)&Qs[n][c4] = qv;
    *(ushort4*)&Ks[n][c4] = kv;
    VTs[c4 + 0][n] = vv.x;
    VTs[c4 + 1][n] = vv.y;
    VTs[c4 + 2][n] = vv.z;
    VTs[c4 + 3][n] = vv.w;
  }
  for (int idx = t; idx < 1024; idx += 256) {
    const int j = idx & 15;
    if (j) VTs[idx >> 4][48 + j] = 0;
  }

  // ---- issue prev/bias to registers (in flight across QK^T: T14) ----
  float prevR[10], biasR[10];
  {
    const float* pv = prev + (long)bh * 2401;
    const float* bm = biasM + h * 2401;
#pragma unroll
    for (int k = 0; k < 10; ++k) {
      const int i = t + 256 * k;
      if (i < 2401) {
        prevR[k] = pv[i];
        biasR[k] = bm[i];
      }
    }
  }

  // barrier #1: drain LDS writes only; vmcnt stays outstanding
  asm volatile("s_waitcnt lgkmcnt(0)" ::: "memory");
  __builtin_amdgcn_s_barrier();
  asm volatile("" ::: "memory");

  // ---- QK^T ----
  bf16x8 af0 = *(const bf16x8*)&Qs[16 * w + lr][lhi * 8];
  bf16x8 af1 = *(const bf16x8*)&Qs[16 * w + lr][32 + lhi * 8];
  f32x4 sacc[4];
#pragma unroll
  for (int tc = 0; tc < 4; ++tc) {
    sacc[tc] = (f32x4){0.f, 0.f, 0.f, 0.f};
    bf16x8 b0 = *(const bf16x8*)&Ks[16 * tc + lr][lhi * 8];
    bf16x8 b1 = *(const bf16x8*)&Ks[16 * tc + lr][32 + lhi * 8];
    sacc[tc] = __builtin_amdgcn_mfma_f32_16x16x32_bf16(af0, b0, sacc[tc], 0, 0, 0);
    sacc[tc] = __builtin_amdgcn_mfma_f32_16x16x32_bf16(af1, b1, sacc[tc], 0, 0, 0);
  }

  // ---- land prev/bias, build SB, publish (barrier #2) ----
  asm volatile("s_waitcnt vmcnt(0)" ::: "memory");
#pragma unroll
  for (int k = 0; k < 10; ++k) {
    const int i = t + 256 * k;
    if (i < 2401) SB[i] = f2bf(prevR[k] + biasR[k]);
  }
  asm volatile("s_waitcnt lgkmcnt(0)" ::: "memory");
  __builtin_amdgcn_s_barrier();
  asm volatile("" ::: "memory");

  // ---- epilogue + softmax (writes SB scores + Ps, both wave-local rows) ----
  u16 (*Ps)[72] = Qs;
  const int nrow0 = 16 * w + 4 * lhi;
  float rs[4];
#pragma unroll
  for (int r = 0; r < 4; ++r) {
    const int row = nrow0 + r;
    const bool rv = row < 49;
    float sv[4];
#pragma unroll
    for (int tc = 0; tc < 4; ++tc) {
      const int col = 16 * tc + lr;
      const bool valid = rv && (col < 49);
      const int sidx = (row < 49 ? row : 48) * 49 + (col < 49 ? col : 48);
      const float pb = bf2f(SB[sidx]);
      const float s = sacc[tc][r] * 0.125f + pb;
      if (valid) SB[sidx] = f2bf(s);
      sv[tc] = valid ? s : -INFINITY;
    }
    float mx = fmaxf(fmaxf(sv[0], sv[1]), fmaxf(sv[2], sv[3]));
#pragma unroll
    for (int off = 8; off; off >>= 1) mx = fmaxf(mx, __shfl_xor(mx, off, 16));
    float e[4], sum = 0.f;
#pragma unroll
    for (int tc = 0; tc < 4; ++tc) {
      e[tc] = __expf(sv[tc] - mx);
      sum += e[tc];
    }
#pragma unroll
    for (int off = 8; off; off >>= 1) sum += __shfl_xor(sum, off, 16);
    rs[r] = 1.0f / sum;
#pragma unroll
    for (int tc = 0; tc < 4; ++tc)
      Ps[row][16 * tc + lr] = rv ? f2bf(e[tc]) : (u16)0;
  }

  // no block barrier: Ps rows are wave-local. Drain own ds_writes.
  asm volatile("s_waitcnt lgkmcnt(0)" ::: "memory");
  __builtin_amdgcn_sched_barrier(0);

  // ---- P*V (pf from own Ps rows; VTs published at barrier #1) ----
  bf16x8 pf0 = *(const bf16x8*)&Ps[16 * w + lr][lhi * 8];
  bf16x8 pf1 = *(const bf16x8*)&Ps[16 * w + lr][32 + lhi * 8];
  f32x4 oacc[4];
#pragma unroll
  for (int dc = 0; dc < 4; ++dc) {
    oacc[dc] = (f32x4){0.f, 0.f, 0.f, 0.f};
    bf16x8 v0 = *(const bf16x8*)&VTs[16 * dc + lr][lhi * 8];
    bf16x8 v1 = *(const bf16x8*)&VTs[16 * dc + lr][32 + lhi * 8];
    oacc[dc] = __builtin_amdgcn_mfma_f32_16x16x32_bf16(pf0, v0, oacc[dc], 0, 0, 0);
    oacc[dc] = __builtin_amdgcn_mfma_f32_16x16x32_bf16(pf1, v1, oacc[dc], 0, 0, 0);
  }

  // ---- repack O into Ps (own rows; dead after pf loads) ----
#pragma unroll
  for (int r = 0; r < 4; ++r) {
    const int row = nrow0 + r;
    if (row < 49) {
#pragma unroll
      for (int dc = 0; dc < 4; ++dc)
        Ps[row][16 * dc + lr] = f2bf(oacc[dc][r] * rs[r]);
    }
  }
  asm volatile("s_waitcnt lgkmcnt(0)" ::: "memory");
  __builtin_amdgcn_sched_barrier(0);

  // ---- per-wave streaming: wave w owns rows [16w, min(16w+16,49)) ----
  {
    const int r0 = 16 * w;
    const int r1 = (16 * w + 16 < 49) ? 16 * w + 16 : 49;
    u16* ob = attn_out + (long)(b * 49) * 768 + h * 64;
    for (int it = l; it < (r1 - r0) * 8; it += 64) {
      const int row = r0 + (it >> 3), cc = (it & 7) << 3;
      *(ulonglong2*)&ob[(long)row * 768 + cc] = *(const ulonglong2*)&Ps[row][cc];
    }
    float* pout = prev_out + (long)bh * 2401;
    for (int i = r0 * 49 + l; i < r1 * 49; i += 64) pout[i] = bf2f(SB[i]);
  }
}

// ---------------- launch ----------------
extern "C" void kernel_launch(void* const* d_in, const int* in_sizes, int n_in,
                              void* d_out, int out_size, void* d_ws, size_t ws_size,
                              hipStream_t stream) {
  const float* x = (const float*)d_in[0];
  const float* prev = (const float*)d_in[1];
  const float* qkv_w = (const float*)d_in[2];
  const float* proj_w = (const float*)d_in[3];
  const float* proj_b = (const float*)d_in[4];
  const float* bias_table = (const float*)d_in[5];
  const int* rel_idx = (const int*)d_in[6];

  const int B = in_sizes[0] / (49 * 768);  // 1024
  const int M = B * 49;                    // 50176 = 196*256

  float* out0 = (float*)d_out;             // [M,768]
  float* out1 = out0 + (size_t)M * 768;    // [B,12,49,49]

  char* ws = (char*)d_ws;
  u16* xbf = (u16*)ws;                                     // M*768 bf16 (reused as attn_out)
  u16* qkvbf = (u16*)(ws + (size_t)M * 768 * 2);           // M*2304 bf16
  u16* qkvwT = (u16*)(ws + (size_t)M * 768 * 2 + (size_t)M * 2304 * 2);  // [2304,768]
  u16* projwT = qkvwT + 2304 * 768;                        // [768,768]
  float* biasM = (float*)(projwT + 768 * 768);             // [12,2401]

  prep<<<2048 + 1728 + 576 + 113, 256, 0, stream>>>(
      x, xbf, M * 768 / 4, qkv_w, qkvwT, proj_w, projwT,
      bias_table, rel_idx, biasM);

  gemm256<true><<<(M / 256) * (2304 / 256), 512, 0, stream>>>(
      xbf, qkvwT, qkvbf, nullptr, M, 2304, 768, 2304 / 256);

  attn_kernel<<<B * 12, 256, 0, stream>>>(qkvbf, prev, biasM, out1, xbf);

  gemm256<false><<<(M / 256) * (768 / 256), 512, 0, stream>>>(
      xbf, projwT, out0, proj_b, M, 768, 768, 768 / 256);
}